// Round 2
// baseline (2703.734 us; speedup 1.0000x reference)
//
#include <hip/hip_runtime.h>
#include <math.h>

// Problem constants (match reference)
constexpr int B   = 256;
constexpr int T   = 16384;
constexpr int K   = 3;
constexpr int TPB = 256;

// ---------------------------------------------------------------------------
// Kernel 1: causal convs (k=8,16,32) in FLOAT64, scaled by 1/sqrt(k).
// Writes f32 u into d_out (output 0) and f64 u into the ws segment buffer.
// ---------------------------------------------------------------------------
__global__ __launch_bounds__(TPB) void conv_kernel(
    const float* __restrict__ x,
    const float* __restrict__ w0f,
    const float* __restrict__ w1f,
    const float* __restrict__ w2f,
    float*  __restrict__ u_out,   // [B][K][T] f32 (absolute t)
    double* __restrict__ u64,     // [B][K][seg] f64 (segment-local t)
    int t_base, int seg)
{
    const int chunks = seg / TPB;
    const int b      = blockIdx.x / chunks;
    const int chunk  = blockIdx.x - b * chunks;
    const int tl0    = chunk * TPB;
    const int tid    = threadIdx.x;

    __shared__ double sx[TPB + 32];
    const float* xb = x + (size_t)b * T;
    for (int i = tid; i < TPB + 32; i += TPB) {
        const int g = t_base + tl0 - 32 + i;
        sx[i] = (g >= 0) ? (double)xb[g] : 0.0;
    }
    __syncthreads();

    const double* wn = &sx[tid + 32];   // wn[d] == x[b, t + d] (f64)

    // out[t] = sum_{i=0}^{k-1} w[i] * x[t + i - (k-1)]  (cross-correlation)
    double a0 = 0.0, a1 = 0.0, a2 = 0.0;
#pragma unroll
    for (int i = 0; i < 8; ++i)  a0 += (double)w0f[i] * wn[i - 7];
#pragma unroll
    for (int i = 0; i < 16; ++i) a1 += (double)w1f[i] * wn[i - 15];
#pragma unroll
    for (int i = 0; i < 32; ++i) a2 += (double)w2f[i] * wn[i - 31];

    const double s8  = 1.0 / sqrt(8.0);   // constant-folded, correctly rounded
    const double s16 = 0.25;
    const double s32 = 1.0 / sqrt(32.0);
    a0 *= s8; a1 *= s16; a2 *= s32;       // GAIN = 1.0 is a no-op

    const int tl = tl0 + tid;
    const int t  = t_base + tl;

    double* ub = u64 + ((size_t)b * K) * seg;
    ub[tl]           = a0;
    ub[seg + tl]     = a1;
    ub[2 * seg + tl] = a2;

    float* uf = u_out + ((size_t)b * K) * T;
    uf[t]         = (float)a0;
    uf[T + t]     = (float)a1;
    uf[2 * T + t] = (float)a2;
}

// ---------------------------------------------------------------------------
// Kernel 2: LIF + top-1 WTA sequential scan in FLOAT64.
// One lane per batch chain (256 chains -> 4 blocks x 64 lanes).
// Reset value v - s*theta == m = v - 1.0 bit-exactly (same single rounding
// numpy performs), so the post-spike state select reuses m.
// ---------------------------------------------------------------------------
__global__ __launch_bounds__(64) void scan_kernel(
    const double* __restrict__ u64,   // [B][K][seg]
    float*  __restrict__ s_out,       // [B][K][T] f32 (absolute t)
    double* __restrict__ vstate,      // [B][K]
    int t_base, int seg)
{
    const int b = blockIdx.x * 64 + threadIdx.x;

    const double* p0 = u64 + ((size_t)b * K) * seg;
    const double* p1 = p0 + seg;
    const double* p2 = p1 + seg;
    float* s0 = s_out + ((size_t)b * K) * T + t_base;
    float* s1 = s0 + T;
    float* s2 = s1 + T;

    double v0, v1, v2;
    if (t_base == 0) {
        v0 = 0.0; v1 = 0.0; v2 = 0.0;
    } else {
        v0 = vstate[b * 3 + 0];
        v1 = vstate[b * 3 + 1];
        v2 = vstate[b * 3 + 2];
    }

#define STEP(U0, U1, U2, O0, O1, O2) do {                         \
    v0 = fma(0.95, v0, (U0));                                     \
    v1 = fma(0.95, v1, (U1));                                     \
    v2 = fma(0.95, v2, (U2));                                     \
    const double m0 = v0 - 1.0, m1 = v1 - 1.0, m2 = v2 - 1.0;     \
    const bool w0_ = (m0 >= m1) & (m0 >= m2);  /* first-index */  \
    const bool w1_ = (!w0_) & (m1 >= m2);      /* argmax ties */  \
    const bool w2_ = (!w0_) & (!w1_);                             \
    const bool f0 = w0_ & (m0 >= 0.0);                            \
    const bool f1 = w1_ & (m1 >= 0.0);                            \
    const bool f2 = w2_ & (m2 >= 0.0);                            \
    v0 = f0 ? m0 : v0;                                            \
    v1 = f1 ? m1 : v1;                                            \
    v2 = f2 ? m2 : v2;                                            \
    (O0) = f0 ? 1.0f : 0.0f;                                      \
    (O1) = f1 ? 1.0f : 0.0f;                                      \
    (O2) = f2 ? 1.0f : 0.0f;                                      \
} while (0)

    for (int t = 0; t < seg; t += 4) {
        const double4 ua = *(const double4*)(p0 + t);
        const double4 ub = *(const double4*)(p1 + t);
        const double4 uc = *(const double4*)(p2 + t);
        float4 r0, r1, r2;
        STEP(ua.x, ub.x, uc.x, r0.x, r1.x, r2.x);
        STEP(ua.y, ub.y, uc.y, r0.y, r1.y, r2.y);
        STEP(ua.z, ub.z, uc.z, r0.z, r1.z, r2.z);
        STEP(ua.w, ub.w, uc.w, r0.w, r1.w, r2.w);
        *(float4*)(s0 + t) = r0;
        *(float4*)(s1 + t) = r1;
        *(float4*)(s2 + t) = r2;
    }
#undef STEP

    vstate[b * 3 + 0] = v0;
    vstate[b * 3 + 1] = v1;
    vstate[b * 3 + 2] = v2;
}

// ---------------------------------------------------------------------------
extern "C" void kernel_launch(void* const* d_in, const int* in_sizes, int n_in,
                              void* d_out, int out_size, void* d_ws, size_t ws_size,
                              hipStream_t stream)
{
    const float* x  = (const float*)d_in[0];
    const float* w0 = (const float*)d_in[1];
    const float* w1 = (const float*)d_in[2];
    const float* w2 = (const float*)d_in[3];
    // d_in[4] = y (unused by the reference outputs)

    float* out   = (float*)d_out;
    float* u_out = out;                        // [B][K][T]
    float* s_out = out + (size_t)B * K * T;    // [B][K][T]

    // Segment length: largest power-of-two chunk of T whose f64 staging
    // buffer (+ v state) fits in the workspace.
    int seg = T;
    while (seg > TPB &&
           ((size_t)B * K * seg * sizeof(double) + (size_t)B * K * sizeof(double)) > ws_size) {
        seg >>= 1;
    }
    double* u64    = (double*)d_ws;
    double* vstate = u64 + (size_t)B * K * seg;

    for (int t0 = 0; t0 < T; t0 += seg) {
        conv_kernel<<<B * (seg / TPB), TPB, 0, stream>>>(x, w0, w1, w2, u_out, u64, t0, seg);
        scan_kernel<<<B / 64, 64, 0, stream>>>(u64, s_out, vstate, t0, seg);
    }
}

// Round 3
// 2080.658 us; speedup vs baseline: 1.2995x; 1.2995x over previous
//
#include <hip/hip_runtime.h>
#include <math.h>

// Problem constants (match reference)
constexpr int B   = 256;
constexpr int T   = 16384;
constexpr int K   = 3;

// ---------------------------------------------------------------------------
// Conv kernel: causal convs (k=8,16,32) in f64 (bit-identical tap order to the
// round-2 kernel that passed). Each block covers 64 batches x 64 timesteps.
//   - writes u f32 to d_out in [B][K][T]   (16-float runs per lane -> full lines)
//   - writes u f64 packed [T/4][B][12] to ws (coalesced across lanes = b)
// ---------------------------------------------------------------------------
__global__ __launch_bounds__(256) void conv_kernel(
    const float* __restrict__ x,
    const float* __restrict__ w0f,
    const float* __restrict__ w1f,
    const float* __restrict__ w2f,
    float*  __restrict__ u_out,   // [B][K][T] f32
    double* __restrict__ u64p)    // [T/4][B][12] f64
{
    const int t0  = blockIdx.x * 64;          // time tile
    const int b0  = blockIdx.y * 64;          // batch tile
    const int tid = threadIdx.x;

    // LDS: x[b0+r][t0-31 .. t0+63]  (95 floats per row, pad row to 97 to
    // break the 96%32==0 all-lanes-one-bank pattern; 97%32==1 -> 2-way free)
    __shared__ float sx[64][97];
    for (int i = tid; i < 64 * 96; i += 256) {
        const int r = i / 96;
        const int c = i - r * 96;
        if (c < 95) {
            const int g = t0 - 31 + c;
            sx[r][c] = (g >= 0) ? x[(size_t)(b0 + r) * T + g] : 0.0f;
        }
    }
    __syncthreads();

    const int b_l = tid & 63;
    const int tg  = tid >> 6;        // 4 groups of 16 timesteps
    const int b   = b0 + b_l;

    const double s8  = 1.0 / sqrt(8.0);
    const double s16 = 0.25;
    const double s32 = 1.0 / sqrt(32.0);

    float fr0[16], fr1[16], fr2[16];

#pragma unroll
    for (int j = 0; j < 16; ++j) {
        const int tl = tg * 16 + j;
        const float* p = &sx[b_l][tl + 31];   // p[d] == x[b][t + d]

        double a0 = 0.0, a1 = 0.0, a2 = 0.0;
#pragma unroll
        for (int i = 0; i < 8; ++i)  a0 += (double)w0f[i] * (double)p[i - 7];
#pragma unroll
        for (int i = 0; i < 16; ++i) a1 += (double)w1f[i] * (double)p[i - 15];
#pragma unroll
        for (int i = 0; i < 32; ++i) a2 += (double)w2f[i] * (double)p[i - 31];
        a0 *= s8; a1 *= s16; a2 *= s32;

        // packed f64 write: pack index t/4, slot (t%4)*3 + k
        const int t  = t0 + tl;
        double* pk = u64p + ((size_t)(t >> 2) * B + b) * 12 + (t & 3) * 3;
        pk[0] = a0; pk[1] = a1; pk[2] = a2;

        fr0[j] = (float)a0; fr1[j] = (float)a1; fr2[j] = (float)a2;
    }

    // f32 u output: per lane 16 consecutive floats per channel = 64 B lines
    float* uf = u_out + (size_t)b * (K * T) + t0 + tg * 16;
#pragma unroll
    for (int q = 0; q < 4; ++q) {
        *(float4*)(uf + q * 4)         = ((float4*)fr0)[q];
        *(float4*)(uf + T + q * 4)     = ((float4*)fr1)[q];
        *(float4*)(uf + 2 * T + q * 4) = ((float4*)fr2)[q];
    }
}

// ---------------------------------------------------------------------------
// Scan kernel: LIF + top-1 WTA, one lane per batch chain (4 blocks x 64).
// Reads packed [T/4][B][12] f64 (coalesced across lanes), prefetches the next
// 16 steps into a shadow register set while computing the current 16.
// Numeric path is IDENTICAL to the round-2 kernel that passed.
// ---------------------------------------------------------------------------
__global__ __launch_bounds__(64) void scan_kernel(
    const double* __restrict__ u64p,  // [T/4][B][12]
    float* __restrict__ s_out)        // [B][K][T] f32
{
    const int b = blockIdx.x * 64 + threadIdx.x;

    double v0 = 0.0, v1 = 0.0, v2 = 0.0;

    double c[48];   // current 16 steps (4 packs x 12)
    // preload packs 0..3
#pragma unroll
    for (int p = 0; p < 4; ++p) {
        const double* src = u64p + ((size_t)p * B + b) * 12;
#pragma unroll
        for (int q = 0; q < 6; ++q)
            ((double2*)c)[p * 6 + q] = ((const double2*)src)[q];
    }

#define STEP(U0, U1, U2, O0, O1, O2) do {                         \
    v0 = fma(0.95, v0, (U0));                                     \
    v1 = fma(0.95, v1, (U1));                                     \
    v2 = fma(0.95, v2, (U2));                                     \
    const double m0 = v0 - 1.0, m1 = v1 - 1.0, m2 = v2 - 1.0;     \
    const bool w0_ = (m0 >= m1) & (m0 >= m2);  /* first-index */  \
    const bool w1_ = (!w0_) & (m1 >= m2);      /* argmax ties */  \
    const bool w2_ = (!w0_) & (!w1_);                             \
    const bool f0 = w0_ & (m0 >= 0.0);                            \
    const bool f1 = w1_ & (m1 >= 0.0);                            \
    const bool f2 = w2_ & (m2 >= 0.0);                            \
    v0 = f0 ? m0 : v0;                                            \
    v1 = f1 ? m1 : v1;                                            \
    v2 = f2 ? m2 : v2;                                            \
    (O0) = f0 ? 1.0f : 0.0f;                                      \
    (O1) = f1 ? 1.0f : 0.0f;                                      \
    (O2) = f2 ? 1.0f : 0.0f;                                      \
} while (0)

    float* sb = s_out + (size_t)b * (K * T);

    for (int tb = 0; tb < T; tb += 16) {
        double n[48];
        const bool more = (tb + 16 < T);
        if (more) {
            // prefetch next 4 packs (independent of the compute below)
#pragma unroll
            for (int p = 0; p < 4; ++p) {
                const double* src = u64p + ((size_t)((tb >> 2) + 4 + p) * B + b) * 12;
#pragma unroll
                for (int q = 0; q < 6; ++q)
                    ((double2*)n)[p * 6 + q] = ((const double2*)src)[q];
            }
        }

        float sp0[16], sp1[16], sp2[16];
#pragma unroll
        for (int j = 0; j < 16; ++j) {
            const int base = (j >> 2) * 12 + (j & 3) * 3;
            STEP(c[base], c[base + 1], c[base + 2], sp0[j], sp1[j], sp2[j]);
        }

        // full-line spike stores: 16 consecutive floats per channel
        float* s0 = sb + tb;
#pragma unroll
        for (int q = 0; q < 4; ++q) {
            *(float4*)(s0 + q * 4)         = ((float4*)sp0)[q];
            *(float4*)(s0 + T + q * 4)     = ((float4*)sp1)[q];
            *(float4*)(s0 + 2 * T + q * 4) = ((float4*)sp2)[q];
        }

        if (more) {
#pragma unroll
            for (int i = 0; i < 48; ++i) c[i] = n[i];
        }
    }
#undef STEP
}

// ---------------------------------------------------------------------------
extern "C" void kernel_launch(void* const* d_in, const int* in_sizes, int n_in,
                              void* d_out, int out_size, void* d_ws, size_t ws_size,
                              hipStream_t stream)
{
    const float* x  = (const float*)d_in[0];
    const float* w0 = (const float*)d_in[1];
    const float* w1 = (const float*)d_in[2];
    const float* w2 = (const float*)d_in[3];
    // d_in[4] = y (unused by the reference outputs)

    float* out   = (float*)d_out;
    float* u_out = out;                        // [B][K][T]
    float* s_out = out + (size_t)B * K * T;    // [B][K][T]

    double* u64p = (double*)d_ws;              // [T/4][B][12] = 100.7 MB (fits: proven round 2)

    dim3 cgrid(T / 64, B / 64);
    conv_kernel<<<cgrid, 256, 0, stream>>>(x, w0, w1, w2, u_out, u64p);
    scan_kernel<<<B / 64, 64, 0, stream>>>(u64p, s_out);
}